// Round 1
// baseline (2715.392 us; speedup 1.0000x reference)
//
#include <hip/hip_runtime.h>
#include <math.h>

#define N_VOX 200000
#define CCH   128
#define KOFF  27

__device__ __forceinline__ float silu_f(float x) {
    return x / (1.0f + expf(-x));
}

// ---------------------------------------------------------------------------
// Kernel 1: time embedding. xe[i] = {feat[i], sin(t*pi*2^k), cos(t*pi*2^k), 0}
// Row N_VOX is the zero sentinel row. f64 trig matches the numpy reference
// (t * 2^k * pi is an integer multiple of pi -> sin ~ 0, cos ~ +-1).
// ---------------------------------------------------------------------------
__global__ void embed_kernel(const float* __restrict__ feat,
                             const int* __restrict__ t,
                             float* __restrict__ xe) {
    int i = blockIdx.x * blockDim.x + threadIdx.x;
    if (i > N_VOX) return;
    float v[8];
    if (i == N_VOX) {
#pragma unroll
        for (int j = 0; j < 8; ++j) v[j] = 0.f;
    } else {
        v[0] = feat[i];
        double td = (double)t[i];
#pragma unroll
        for (int kk = 0; kk < 3; ++kk) {
            double ang = td * (3.14159265358979323846 * (double)(1 << kk));
            v[1 + kk] = (float)sin(ang);
            v[4 + kk] = (float)cos(ang);
        }
        v[7] = 0.f;
    }
    float4* dst = (float4*)(xe + (size_t)i * 8);
    dst[0] = make_float4(v[0], v[1], v[2], v[3]);
    dst[1] = make_float4(v[4], v[5], v[6], v[7]);
}

// ---------------------------------------------------------------------------
// Kernel 2: conv1 (27 offsets, Cin=7, Cout=128) + SiLU -> h1[(N+1)*128]
// 64 voxels per block of 256 threads; thread (vrow, ccol) computes 4 vox x 8 ch.
// ---------------------------------------------------------------------------
__global__ __launch_bounds__(256) void conv1_kernel(
    const float* __restrict__ xe, const int* __restrict__ nidx,
    const float* __restrict__ W1, const float* __restrict__ b1,
    float* __restrict__ h1) {
    __shared__ float A[64][9];     // gathered xe rows (pad 9 -> conflict-free)
    __shared__ float B[7][128];    // W1[k]
    __shared__ int idxs[64];

    int tid = threadIdx.x;
    int v0 = blockIdx.x * 64;
    int vrow = tid >> 4;           // 0..15
    int ccol = tid & 15;           // 0..15

    float acc[4][8];
#pragma unroll
    for (int j = 0; j < 4; ++j)
#pragma unroll
        for (int q = 0; q < 8; ++q) acc[j][q] = 0.f;

    for (int k = 0; k < KOFF; ++k) {
        if (tid < 64) idxs[tid] = nidx[(size_t)k * N_VOX + v0 + tid];
        // stage W1[k]: 7*128 floats
        for (int u = tid; u < 7 * 128; u += 256)
            (&B[0][0])[u] = W1[(size_t)k * 7 * 128 + u];
        __syncthreads();
        // gather 64 rows x 8 (only 7 used)
        {
            int v = tid >> 2, part = tid & 3;
            int row = idxs[v];
            const float* src = xe + (size_t)row * 8 + part * 2;
            A[v][part * 2] = src[0];
            A[v][part * 2 + 1] = src[1];
        }
        __syncthreads();
#pragma unroll
        for (int ci = 0; ci < 7; ++ci) {
            float a0 = A[vrow * 4 + 0][ci];
            float a1 = A[vrow * 4 + 1][ci];
            float a2 = A[vrow * 4 + 2][ci];
            float a3 = A[vrow * 4 + 3][ci];
#pragma unroll
            for (int q = 0; q < 8; ++q) {
                float w = B[ci][ccol * 8 + q];
                acc[0][q] += a0 * w;
                acc[1][q] += a1 * w;
                acc[2][q] += a2 * w;
                acc[3][q] += a3 * w;
            }
        }
        __syncthreads();   // protect A/B/idxs before next k overwrites
    }
#pragma unroll
    for (int j = 0; j < 4; ++j) {
        int v = v0 + vrow * 4 + j;
#pragma unroll
        for (int q = 0; q < 8; ++q) {
            int c = ccol * 8 + q;
            h1[(size_t)v * CCH + c] = silu_f(acc[j][q] + b1[c]);
        }
    }
    // zero sentinel row N (gathers with idx==N read zeros)
    if (blockIdx.x == 0 && tid < CCH) h1[(size_t)N_VOX * CCH + tid] = 0.f;
}

// ---------------------------------------------------------------------------
// Kernel 3: conv2 (27 offsets, 128x128) + SiLU -> h2[N*128]. The hot kernel.
// 64 voxels x 128 out-ch per block (256 threads, 4x8 fp32 acc per thread).
// ---------------------------------------------------------------------------
__global__ __launch_bounds__(256) void conv2_kernel(
    const float* __restrict__ h1, const int* __restrict__ nidx,
    const float* __restrict__ W2, const float* __restrict__ b2,
    float* __restrict__ h2) {
    __shared__ float A[64][132];   // gathered h1 rows, padded stride
    __shared__ float Bs[32][128];  // W2[k] chunk (32 ci rows)
    __shared__ int idxs[64];

    int tid = threadIdx.x;
    int v0 = blockIdx.x * 64;
    int vrow = tid >> 4;
    int ccol = tid & 15;

    float acc[4][8];
#pragma unroll
    for (int j = 0; j < 4; ++j)
#pragma unroll
        for (int q = 0; q < 8; ++q) acc[j][q] = 0.f;

    for (int k = 0; k < KOFF; ++k) {
        if (tid < 64) idxs[tid] = nidx[(size_t)k * N_VOX + v0 + tid];
        __syncthreads();
        // gather 64 rows x 128 floats as float4s (4 threads per row)
        {
            int v = tid >> 2, part = tid & 3;
            long row = idxs[v];
            const float4* src = (const float4*)(h1 + row * 128 + part * 32);
            float4* dst = (float4*)(&A[v][part * 32]);
#pragma unroll
            for (int u = 0; u < 8; ++u) dst[u] = src[u];
        }
        for (int cc = 0; cc < 4; ++cc) {
            // stage 32 ci-rows of W2[k]
            const float4* wsrc =
                (const float4*)(W2 + ((size_t)k * 128 + cc * 32) * 128);
            float4* bdst = (float4*)(&Bs[0][0]);
#pragma unroll
            for (int u = 0; u < 4; ++u) bdst[tid + 256 * u] = wsrc[tid + 256 * u];
            __syncthreads();
#pragma unroll
            for (int ci = 0; ci < 32; ++ci) {
                float a0 = A[vrow * 4 + 0][cc * 32 + ci];
                float a1 = A[vrow * 4 + 1][cc * 32 + ci];
                float a2 = A[vrow * 4 + 2][cc * 32 + ci];
                float a3 = A[vrow * 4 + 3][cc * 32 + ci];
                float4 bb0 = *(const float4*)&Bs[ci][ccol * 8];
                float4 bb1 = *(const float4*)&Bs[ci][ccol * 8 + 4];
                acc[0][0] += a0 * bb0.x; acc[0][1] += a0 * bb0.y;
                acc[0][2] += a0 * bb0.z; acc[0][3] += a0 * bb0.w;
                acc[0][4] += a0 * bb1.x; acc[0][5] += a0 * bb1.y;
                acc[0][6] += a0 * bb1.z; acc[0][7] += a0 * bb1.w;
                acc[1][0] += a1 * bb0.x; acc[1][1] += a1 * bb0.y;
                acc[1][2] += a1 * bb0.z; acc[1][3] += a1 * bb0.w;
                acc[1][4] += a1 * bb1.x; acc[1][5] += a1 * bb1.y;
                acc[1][6] += a1 * bb1.z; acc[1][7] += a1 * bb1.w;
                acc[2][0] += a2 * bb0.x; acc[2][1] += a2 * bb0.y;
                acc[2][2] += a2 * bb0.z; acc[2][3] += a2 * bb0.w;
                acc[2][4] += a2 * bb1.x; acc[2][5] += a2 * bb1.y;
                acc[2][6] += a2 * bb1.z; acc[2][7] += a2 * bb1.w;
                acc[3][0] += a3 * bb0.x; acc[3][1] += a3 * bb0.y;
                acc[3][2] += a3 * bb0.z; acc[3][3] += a3 * bb0.w;
                acc[3][4] += a3 * bb1.x; acc[3][5] += a3 * bb1.y;
                acc[3][6] += a3 * bb1.z; acc[3][7] += a3 * bb1.w;
            }
            __syncthreads();
        }
    }
#pragma unroll
    for (int j = 0; j < 4; ++j) {
        int v = v0 + vrow * 4 + j;
#pragma unroll
        for (int q = 0; q < 8; ++q) {
            int c = ccol * 8 + q;
            h2[(size_t)v * CCH + c] = silu_f(acc[j][q] + b2[c]);
        }
    }
}

// ---------------------------------------------------------------------------
// Kernel 4: h3 = silu(h2 @ W3 + b3); out = h3 @ W4 + b4. 4 voxels per block.
// ---------------------------------------------------------------------------
__global__ __launch_bounds__(128) void tail_kernel(
    const float* __restrict__ h2, const float* __restrict__ W3,
    const float* __restrict__ b3, const float* __restrict__ W4,
    const float* __restrict__ b4, float* __restrict__ out) {
    __shared__ float H[4][132];
    __shared__ float R[4][128];
    int tid = threadIdx.x;
    int v0 = blockIdx.x * 4;
    {
        int r = tid >> 5, part = tid & 31;
        *(float4*)&H[r][part * 4] =
            *(const float4*)(h2 + (size_t)(v0 + r) * CCH + part * 4);
    }
    __syncthreads();
    int c = tid;
    float a0 = b3[c], a1 = b3[c], a2 = b3[c], a3 = b3[c];
    for (int ci = 0; ci < 128; ++ci) {
        float w = W3[(size_t)ci * 128 + c];
        a0 += H[0][ci] * w;
        a1 += H[1][ci] * w;
        a2 += H[2][ci] * w;
        a3 += H[3][ci] * w;
    }
    float w4 = W4[c];
    R[0][c] = silu_f(a0) * w4;
    R[1][c] = silu_f(a1) * w4;
    R[2][c] = silu_f(a2) * w4;
    R[3][c] = silu_f(a3) * w4;
    __syncthreads();
    for (int s = 64; s >= 1; s >>= 1) {
        if (c < s) {
#pragma unroll
            for (int v = 0; v < 4; ++v) R[v][c] += R[v][c + s];
        }
        __syncthreads();
    }
    if (tid < 4) out[v0 + tid] = R[tid][0] + b4[0];
}

// ---------------------------------------------------------------------------
extern "C" void kernel_launch(void* const* d_in, const int* in_sizes, int n_in,
                              void* d_out, int out_size, void* d_ws,
                              size_t ws_size, hipStream_t stream) {
    const float* feat = (const float*)d_in[0];
    const int* t      = (const int*)d_in[1];
    const int* nidx   = (const int*)d_in[2];
    const float* W1   = (const float*)d_in[3];
    const float* b1   = (const float*)d_in[4];
    const float* W2   = (const float*)d_in[5];
    const float* b2   = (const float*)d_in[6];
    const float* W3   = (const float*)d_in[7];
    const float* b3   = (const float*)d_in[8];
    const float* W4   = (const float*)d_in[9];
    const float* b4   = (const float*)d_in[10];
    float* out = (float*)d_out;

    char* ws = (char*)d_ws;
    size_t off = 0;
    float* xe = (float*)(ws + off);
    off += ((size_t)(N_VOX + 1) * 8 * 4 + 255) & ~(size_t)255;
    float* h1 = (float*)(ws + off);
    off += ((size_t)(N_VOX + 1) * CCH * 4 + 255) & ~(size_t)255;
    float* h2 = (float*)(ws + off);

    embed_kernel<<<(N_VOX + 1 + 255) / 256, 256, 0, stream>>>(feat, t, xe);
    conv1_kernel<<<N_VOX / 64, 256, 0, stream>>>(xe, nidx, W1, b1, h1);
    conv2_kernel<<<N_VOX / 64, 256, 0, stream>>>(h1, nidx, W2, b2, h2);
    tail_kernel<<<N_VOX / 4, 128, 0, stream>>>(h2, W3, b3, W4, b4, out);
}

// Round 2
// 639.688 us; speedup vs baseline: 4.2449x; 4.2449x over previous
//
#include <hip/hip_runtime.h>
#include <math.h>

#define N_VOX 200000
#define CCH   128
#define KOFF  27

typedef __attribute__((ext_vector_type(8))) short bf16x8;
typedef __attribute__((ext_vector_type(4))) float f32x4;

__device__ __forceinline__ float silu_f(float x) {
    return x / (1.0f + expf(-x));
}

// fp32 -> bf16 round-to-nearest-even
__device__ __forceinline__ unsigned short f2bf(float x) {
    unsigned int u = __float_as_uint(x);
    u = (u + 0x7FFFu + ((u >> 16) & 1u)) >> 16;
    return (unsigned short)u;
}

// ---------------------------------------------------------------------------
// Kernel 1: time embedding, fp32 trig matching the numpy reference:
// freqs_k = float32(pi) * 2^k (exact scaling), ang = float32(t) * freq, sinf.
// Row N_VOX is the zero sentinel row.
// ---------------------------------------------------------------------------
__global__ void embed_kernel(const float* __restrict__ feat,
                             const int* __restrict__ t,
                             float* __restrict__ xe) {
    int i = blockIdx.x * blockDim.x + threadIdx.x;
    if (i > N_VOX) return;
    float v[8];
    if (i == N_VOX) {
#pragma unroll
        for (int j = 0; j < 8; ++j) v[j] = 0.f;
    } else {
        v[0] = feat[i];
        float tf = (float)t[i];
#pragma unroll
        for (int kk = 0; kk < 3; ++kk) {
            float freq = (float)M_PI * (float)(1 << kk);
            float ang = tf * freq;
            v[1 + kk] = sinf(ang);
            v[4 + kk] = cosf(ang);
        }
        v[7] = 0.f;
    }
    float4* dst = (float4*)(xe + (size_t)i * 8);
    dst[0] = make_float4(v[0], v[1], v[2], v[3]);
    dst[1] = make_float4(v[4], v[5], v[6], v[7]);
}

// ---------------------------------------------------------------------------
// Kernel 1b: permute W2 (fp32 [27][128][128]) into MFMA-fragment-linear bf16:
// W2f[(((k*4+kk)*8+nf)*64+l)*8 + j] = bf16(W2[k][kk*32+(l>>4)*8+j][nf*16+(l&15)])
// so a B-fragment load in conv2 is one coalesced 16B/lane read.
// ---------------------------------------------------------------------------
__global__ void convert_w2(const float* __restrict__ W2,
                           unsigned short* __restrict__ W2f) {
    int g = blockIdx.x * 256 + threadIdx.x;   // 0 .. 27*4*8*64-1
    int l = g & 63;
    int rest = g >> 6;            // (k*4+kk)*8 + nf
    int nf = rest & 7;
    int kkk = rest >> 3;          // k*4+kk
    int k = kkk >> 2, kk = kkk & 3;
    int ci0 = kk * 32 + (l >> 4) * 8;
    int co = nf * 16 + (l & 15);
    union { unsigned short u[8]; int4 v; } out;
#pragma unroll
    for (int j = 0; j < 8; ++j) {
        float w = W2[((size_t)k * CCH + ci0 + j) * CCH + co];
        out.u[j] = f2bf(w);
    }
    *(int4*)(W2f + (size_t)g * 8) = out.v;
}

// ---------------------------------------------------------------------------
// Kernel 2: conv1 (27 offsets, Cin=7, Cout=128) + SiLU -> h1b bf16 [(N+1)*128]
// ---------------------------------------------------------------------------
__global__ __launch_bounds__(256) void conv1_kernel(
    const float* __restrict__ xe, const int* __restrict__ nidx,
    const float* __restrict__ W1, const float* __restrict__ b1,
    unsigned short* __restrict__ h1b) {
    __shared__ float A[64][9];
    __shared__ float B[7][128];
    __shared__ int idxs[64];

    int tid = threadIdx.x;
    int v0 = blockIdx.x * 64;
    int vrow = tid >> 4;
    int ccol = tid & 15;

    float acc[4][8];
#pragma unroll
    for (int j = 0; j < 4; ++j)
#pragma unroll
        for (int q = 0; q < 8; ++q) acc[j][q] = 0.f;

    for (int k = 0; k < KOFF; ++k) {
        if (tid < 64) idxs[tid] = nidx[(size_t)k * N_VOX + v0 + tid];
        for (int u = tid; u < 7 * 128; u += 256)
            (&B[0][0])[u] = W1[(size_t)k * 7 * 128 + u];
        __syncthreads();
        {
            int v = tid >> 2, part = tid & 3;
            int row = idxs[v];
            const float* src = xe + (size_t)row * 8 + part * 2;
            A[v][part * 2] = src[0];
            A[v][part * 2 + 1] = src[1];
        }
        __syncthreads();
#pragma unroll
        for (int ci = 0; ci < 7; ++ci) {
            float a0 = A[vrow * 4 + 0][ci];
            float a1 = A[vrow * 4 + 1][ci];
            float a2 = A[vrow * 4 + 2][ci];
            float a3 = A[vrow * 4 + 3][ci];
#pragma unroll
            for (int q = 0; q < 8; ++q) {
                float w = B[ci][ccol * 8 + q];
                acc[0][q] += a0 * w;
                acc[1][q] += a1 * w;
                acc[2][q] += a2 * w;
                acc[3][q] += a3 * w;
            }
        }
        __syncthreads();
    }
#pragma unroll
    for (int j = 0; j < 4; ++j) {
        int v = v0 + vrow * 4 + j;
        union { unsigned short u[8]; int4 v4; } pk;
#pragma unroll
        for (int q = 0; q < 8; ++q) {
            int c = ccol * 8 + q;
            pk.u[q] = f2bf(silu_f(acc[j][q] + b1[c]));
        }
        *(int4*)(h1b + (size_t)v * CCH + ccol * 8) = pk.v4;
    }
    if (blockIdx.x == 0 && tid < CCH) h1b[(size_t)N_VOX * CCH + tid] = 0;
}

// ---------------------------------------------------------------------------
// Kernel 3: conv2 via bf16 MFMA. 128 voxels x 128 out-ch per block, 4 waves,
// each wave a 64x64 tile (M_rep=4, N_rep=4 of 16x16x32).
// A staged in LDS with XOR chunk swizzle: physical slot s = (c&8)|((c&7)^(r&7))
// (linear ds_write from inverse-permuted global source; swizzled ds_read).
// ---------------------------------------------------------------------------
__global__ __launch_bounds__(256) void conv2_mfma(
    const unsigned short* __restrict__ h1b, const int* __restrict__ nidx,
    const unsigned short* __restrict__ W2f, const float* __restrict__ b2,
    float* __restrict__ h2) {
    __shared__ int4 Abuf[128 * 16];   // 32 KB: row r, 16B-slot s at [r*16+s]
    __shared__ int idxsL[2][128];

    int tid = threadIdx.x;
    int l = tid & 63;
    int w = tid >> 6;
    int mw = w >> 1, nwv = w & 1;
    int v0 = blockIdx.x * 128;

    f32x4 acc[4][4];
#pragma unroll
    for (int m = 0; m < 4; ++m)
#pragma unroll
        for (int n = 0; n < 4; ++n) acc[m][n] = (f32x4)0.f;

    float bias[4];
#pragma unroll
    for (int n = 0; n < 4; ++n) bias[n] = b2[nwv * 64 + n * 16 + (l & 15)];

    if (tid < 128) {
        int v = v0 + tid;
        idxsL[0][tid] = (v < N_VOX) ? nidx[v] : N_VOX;
    }
    __syncthreads();

    for (int k = 0; k < KOFF; ++k) {
        int cur = k & 1;
        int nexti = N_VOX;
        if (tid < 128) {
            int v = v0 + tid;
            if (k + 1 < KOFF && v < N_VOX)
                nexti = nidx[(size_t)(k + 1) * N_VOX + v];
        }
        // gather 128 rows x 256B into swizzled LDS (linear writes)
        {
            int s = l & 15;
            int rb = w * 32 + (l >> 4);
#pragma unroll
            for (int u = 0; u < 8; ++u) {
                int r = rb + u * 4;
                int c = (s & 8) | ((s & 7) ^ (r & 7));
                int idx = idxsL[cur][r];
                Abuf[r * 16 + s] =
                    *(const int4*)(h1b + (size_t)idx * CCH + c * 8);
            }
        }
        __syncthreads();
        if (tid < 128) idxsL[cur ^ 1][tid] = nexti;

#pragma unroll
        for (int kk = 0; kk < 4; ++kk) {
            bf16x8 a[4], b[4];
#pragma unroll
            for (int m = 0; m < 4; ++m) {
                int r = mw * 64 + m * 16 + (l & 15);
                int c = kk * 4 + (l >> 4);
                int s = (c & 8) | ((c & 7) ^ (r & 7));
                a[m] = *(const bf16x8*)&Abuf[r * 16 + s];
            }
            size_t base = (size_t)(k * 4 + kk) * 8 * 64 * 8;
#pragma unroll
            for (int n = 0; n < 4; ++n) {
                int nf = nwv * 4 + n;
                b[n] = *(const bf16x8*)(W2f + base + ((size_t)nf * 64 + l) * 8);
            }
#pragma unroll
            for (int m = 0; m < 4; ++m)
#pragma unroll
                for (int n = 0; n < 4; ++n)
                    acc[m][n] = __builtin_amdgcn_mfma_f32_16x16x32_bf16(
                        a[m], b[n], acc[m][n], 0, 0, 0);
        }
        __syncthreads();
    }

#pragma unroll
    for (int m = 0; m < 4; ++m) {
        int vbase = v0 + mw * 64 + m * 16 + (l >> 4) * 4;
#pragma unroll
        for (int n = 0; n < 4; ++n) {
            int ch = nwv * 64 + n * 16 + (l & 15);
            f32x4 d = acc[m][n];
#pragma unroll
            for (int r = 0; r < 4; ++r) {
                int v = vbase + r;
                if (v < N_VOX)
                    h2[(size_t)v * CCH + ch] = silu_f(d[r] + bias[n]);
            }
        }
    }
}

// ---------------------------------------------------------------------------
// Kernel 4: h3 = silu(h2 @ W3 + b3); out = h3 @ W4 + b4. 4 voxels per block.
// ---------------------------------------------------------------------------
__global__ __launch_bounds__(128) void tail_kernel(
    const float* __restrict__ h2, const float* __restrict__ W3,
    const float* __restrict__ b3, const float* __restrict__ W4,
    const float* __restrict__ b4, float* __restrict__ out) {
    __shared__ float H[4][132];
    __shared__ float R[4][128];
    int tid = threadIdx.x;
    int v0 = blockIdx.x * 4;
    {
        int r = tid >> 5, part = tid & 31;
        *(float4*)&H[r][part * 4] =
            *(const float4*)(h2 + (size_t)(v0 + r) * CCH + part * 4);
    }
    __syncthreads();
    int c = tid;
    float a0 = b3[c], a1 = b3[c], a2 = b3[c], a3 = b3[c];
    for (int ci = 0; ci < 128; ++ci) {
        float w = W3[(size_t)ci * 128 + c];
        a0 += H[0][ci] * w;
        a1 += H[1][ci] * w;
        a2 += H[2][ci] * w;
        a3 += H[3][ci] * w;
    }
    float w4 = W4[c];
    R[0][c] = silu_f(a0) * w4;
    R[1][c] = silu_f(a1) * w4;
    R[2][c] = silu_f(a2) * w4;
    R[3][c] = silu_f(a3) * w4;
    __syncthreads();
    for (int s = 64; s >= 1; s >>= 1) {
        if (c < s) {
#pragma unroll
            for (int v = 0; v < 4; ++v) R[v][c] += R[v][c + s];
        }
        __syncthreads();
    }
    if (tid < 4) out[v0 + tid] = R[tid][0] + b4[0];
}

// ---------------------------------------------------------------------------
extern "C" void kernel_launch(void* const* d_in, const int* in_sizes, int n_in,
                              void* d_out, int out_size, void* d_ws,
                              size_t ws_size, hipStream_t stream) {
    const float* feat = (const float*)d_in[0];
    const int* t      = (const int*)d_in[1];
    const int* nidx   = (const int*)d_in[2];
    const float* W1   = (const float*)d_in[3];
    const float* b1   = (const float*)d_in[4];
    const float* W2   = (const float*)d_in[5];
    const float* b2   = (const float*)d_in[6];
    const float* W3   = (const float*)d_in[7];
    const float* b3   = (const float*)d_in[8];
    const float* W4   = (const float*)d_in[9];
    const float* b4   = (const float*)d_in[10];
    float* out = (float*)d_out;

    char* ws = (char*)d_ws;
    size_t off = 0;
    float* xe = (float*)(ws + off);
    off += ((size_t)(N_VOX + 1) * 8 * 4 + 255) & ~(size_t)255;
    unsigned short* h1b = (unsigned short*)(ws + off);
    off += ((size_t)(N_VOX + 1) * CCH * 2 + 255) & ~(size_t)255;
    float* h2 = (float*)(ws + off);
    off += ((size_t)N_VOX * CCH * 4 + 255) & ~(size_t)255;
    unsigned short* W2f = (unsigned short*)(ws + off);

    embed_kernel<<<(N_VOX + 1 + 255) / 256, 256, 0, stream>>>(feat, t, xe);
    convert_w2<<<(KOFF * 4 * 8 * 64) / 256, 256, 0, stream>>>(W2, W2f);
    conv1_kernel<<<N_VOX / 64, 256, 0, stream>>>(xe, nidx, W1, b1, h1b);
    conv2_mfma<<<(N_VOX + 127) / 128, 256, 0, stream>>>(h1b, nidx, W2f, b2, h2);
    tail_kernel<<<N_VOX / 4, 128, 0, stream>>>(h2, W3, b3, W4, b4, out);
}

// Round 3
// 333.135 us; speedup vs baseline: 8.1510x; 1.9202x over previous
//
#include <hip/hip_runtime.h>
#include <math.h>

#define N_VOX 200000
#define CCH   128
#define KOFF  27

typedef __attribute__((ext_vector_type(8))) short bf16x8;
typedef __attribute__((ext_vector_type(4))) float f32x4;

__device__ __forceinline__ float silu_f(float x) {
    return x / (1.0f + expf(-x));
}
__device__ __forceinline__ unsigned short f2bf(float x) {
    unsigned int u = __float_as_uint(x);
    u = (u + 0x7FFFu + ((u >> 16) & 1u)) >> 16;
    return (unsigned short)u;
}
// bijective XCD-aware block swizzle (m204 variant)
__device__ __forceinline__ int xcd_swz(int orig, int nwg) {
    int q = nwg >> 3, r = nwg & 7;
    int xcd = orig & 7, pos = orig >> 3;
    return (xcd < r ? xcd * (q + 1) : r * (q + 1) + (xcd - r) * q) + pos;
}

// ---------------------------------------------------------------------------
// Kernel 1: time embedding -> bf16 xeb[(N+1)][8] = {feat, sin*3, cos*3, 0}
// ---------------------------------------------------------------------------
__global__ void embed_kernel(const float* __restrict__ feat,
                             const int* __restrict__ t,
                             unsigned short* __restrict__ xeb) {
    int i = blockIdx.x * blockDim.x + threadIdx.x;
    if (i > N_VOX) return;
    union { unsigned short u[8]; int4 v; } o;
    if (i == N_VOX) {
        o.v = make_int4(0, 0, 0, 0);
    } else {
        o.u[0] = f2bf(feat[i]);
        float tf = (float)t[i];
#pragma unroll
        for (int kk = 0; kk < 3; ++kk) {
            float freq = (float)M_PI * (float)(1 << kk);
            float ang = tf * freq;
            o.u[1 + kk] = f2bf(sinf(ang));
            o.u[4 + kk] = f2bf(cosf(ang));
        }
        o.u[7] = 0;
    }
    *(int4*)(xeb + (size_t)i * 8) = o.v;
}

// ---------------------------------------------------------------------------
// Weight repacks to MFMA-fragment-linear bf16 (B-operand layout).
// ---------------------------------------------------------------------------
__global__ void convert_w1(const float* __restrict__ W1,
                           unsigned short* __restrict__ W1f) {
    int g = blockIdx.x * 256 + threadIdx.x;   // 0..7*8*64-1
    if (g >= 7 * 8 * 64) return;
    int l = g & 63;
    int rest = g >> 6;
    int nf = rest & 7;
    int kk = rest >> 3;                        // 0..6
    int o = kk * 4 + (l >> 4);                 // offset id
    int co = nf * 16 + (l & 15);
    union { unsigned short u[8]; int4 v; } out;
#pragma unroll
    for (int j = 0; j < 8; ++j) {
        float w = 0.f;
        if (o < KOFF && j < 7) w = W1[((size_t)o * 7 + j) * CCH + co];
        out.u[j] = f2bf(w);
    }
    *(int4*)(W1f + (size_t)g * 8) = out.v;
}

__global__ void convert_w2(const float* __restrict__ W2,
                           unsigned short* __restrict__ W2f) {
    int g = blockIdx.x * 256 + threadIdx.x;   // 0..27*4*8*64-1
    int l = g & 63;
    int rest = g >> 6;
    int nf = rest & 7;
    int kkk = rest >> 3;
    int k = kkk >> 2, kk = kkk & 3;
    int ci0 = kk * 32 + (l >> 4) * 8;
    int co = nf * 16 + (l & 15);
    union { unsigned short u[8]; int4 v; } out;
#pragma unroll
    for (int j = 0; j < 8; ++j)
        out.u[j] = f2bf(W2[((size_t)k * CCH + ci0 + j) * CCH + co]);
    *(int4*)(W2f + (size_t)g * 8) = out.v;
}

__global__ void convert_w3(const float* __restrict__ W3,
                           unsigned short* __restrict__ W3f) {
    int g = blockIdx.x * 256 + threadIdx.x;   // 0..4*8*64-1
    if (g >= 4 * 8 * 64) return;
    int l = g & 63;
    int rest = g >> 6;
    int nf = rest & 7;
    int kk = rest >> 3;
    int ci0 = kk * 32 + (l >> 4) * 8;
    int co = nf * 16 + (l & 15);
    union { unsigned short u[8]; int4 v; } out;
#pragma unroll
    for (int j = 0; j < 8; ++j)
        out.u[j] = f2bf(W3[(size_t)(ci0 + j) * CCH + co]);
    *(int4*)(W3f + (size_t)g * 8) = out.v;
}

// ---------------------------------------------------------------------------
// Kernel 2: conv1 via MFMA. 128 vox x 128 ch per block, K = 7 steps of 32
// (4 offsets x 8 in-ch each, zero-padded). Double-buffered LDS + reg prefetch.
// ---------------------------------------------------------------------------
__global__ __launch_bounds__(256) void conv1_mfma(
    const unsigned short* __restrict__ xeb, const int* __restrict__ nidx,
    const unsigned short* __restrict__ W1f, const float* __restrict__ b1,
    unsigned short* __restrict__ h1b) {
    __shared__ int4 bufmem[2048];       // dbuf: 2 x 128 rows x 5 slots; H-tile reuse
    __shared__ int idxAll[128 * 28];

    int tid = threadIdx.x;
    int l = tid & 63, w = tid >> 6;
    int mw = w >> 1, nwv = w & 1;
    int wg = xcd_swz(blockIdx.x, gridDim.x);
    int v0 = wg * 128;

    for (int g = tid; g < KOFF * 128; g += 256) {
        int k = g >> 7, vi = g & 127;
        int v = v0 + vi;
        idxAll[vi * 28 + k] = (v < N_VOX) ? nidx[(size_t)k * N_VOX + v] : N_VOX;
    }
    if (tid < 128) idxAll[tid * 28 + 27] = N_VOX;   // pad offset
    __syncthreads();

    f32x4 acc[4][4];
#pragma unroll
    for (int m = 0; m < 4; ++m)
#pragma unroll
        for (int n = 0; n < 4; ++n) acc[m][n] = (f32x4)0.f;

    // prologue: stage kk=0
    {
        int4 g0[2]; int rr[2], cc[2];
#pragma unroll
        for (int u = 0; u < 2; ++u) {
            int q = u * 256 + tid;
            int r = q >> 2, oo = q & 3;
            int idx = idxAll[r * 28 + oo];
            g0[u] = *(const int4*)(xeb + (size_t)idx * 8);
            rr[u] = r; cc[u] = oo ^ (r & 3);
        }
#pragma unroll
        for (int u = 0; u < 2; ++u) bufmem[rr[u] * 5 + cc[u]] = g0[u];
    }
    __syncthreads();

    for (int kk = 0; kk < 7; ++kk) {
        int cur = kk & 1;
        int4 gg[2]; int rr[2], cc[2];
        if (kk < 6) {
#pragma unroll
            for (int u = 0; u < 2; ++u) {
                int q = u * 256 + tid;
                int r = q >> 2, oo = q & 3;
                int idx = idxAll[r * 28 + (kk + 1) * 4 + oo];
                gg[u] = *(const int4*)(xeb + (size_t)idx * 8);
                rr[u] = r; cc[u] = oo ^ (r & 3);
            }
        }
        bf16x8 a[4], b[4];
#pragma unroll
        for (int n = 0; n < 4; ++n) {
            int nf = nwv * 4 + n;
            b[n] = *(const bf16x8*)(W1f + ((size_t)(kk * 8 + nf) * 64 + l) * 8);
        }
#pragma unroll
        for (int m = 0; m < 4; ++m) {
            int r = mw * 64 + m * 16 + (l & 15);
            int c = l >> 4;
            a[m] = *(const bf16x8*)&bufmem[cur * 640 + r * 5 + (c ^ (r & 3))];
        }
#pragma unroll
        for (int m = 0; m < 4; ++m)
#pragma unroll
            for (int n = 0; n < 4; ++n)
                acc[m][n] = __builtin_amdgcn_mfma_f32_16x16x32_bf16(
                    a[m], b[n], acc[m][n], 0, 0, 0);
        if (kk < 6) {
#pragma unroll
            for (int u = 0; u < 2; ++u)
                bufmem[(cur ^ 1) * 640 + rr[u] * 5 + cc[u]] = gg[u];
        }
        __syncthreads();
    }

    // epilogue: H = bf16(silu(acc + b1)) into swizzled LDS tile, coalesced store
    float bias[4];
#pragma unroll
    for (int n = 0; n < 4; ++n) bias[n] = b1[nwv * 64 + n * 16 + (l & 15)];
    unsigned short* H16 = (unsigned short*)bufmem;
#pragma unroll
    for (int m = 0; m < 4; ++m) {
        int rbase = mw * 64 + m * 16 + (l >> 4) * 4;
#pragma unroll
        for (int n = 0; n < 4; ++n) {
            int ch = nwv * 64 + n * 16 + (l & 15);
            int c = ch >> 3;
            f32x4 d = acc[m][n];
#pragma unroll
            for (int ri = 0; ri < 4; ++ri) {
                int r = rbase + ri;
                int s = (c & 8) | ((c & 7) ^ (r & 7));
                H16[r * 128 + s * 8 + (ch & 7)] = f2bf(silu_f(d[ri] + bias[n]));
            }
        }
    }
    __syncthreads();
#pragma unroll
    for (int u = 0; u < 8; ++u) {
        int q = u * 256 + tid;
        int r = q >> 4, s = q & 15;
        int c = (s & 8) | ((s & 7) ^ (r & 7));
        int v = v0 + r;
        if (v < N_VOX)
            *(int4*)(h1b + (size_t)v * CCH + c * 8) = bufmem[r * 16 + s];
    }
    if (blockIdx.x == 0 && tid < 16)
        *(int4*)(h1b + (size_t)N_VOX * CCH + tid * 8) = make_int4(0, 0, 0, 0);
}

// ---------------------------------------------------------------------------
// Kernel 3: conv2 via MFMA + fully fused tail (W3+SiLU+W4) -> out directly.
// 128 vox x 128 ch per block; dbuf LDS A-tile; reg-prefetch gathers; one
// __syncthreads per offset.
// ---------------------------------------------------------------------------
__global__ __launch_bounds__(256) void conv2_mfma(
    const unsigned short* __restrict__ h1b, const int* __restrict__ nidx,
    const unsigned short* __restrict__ W2f, const float* __restrict__ b2,
    const unsigned short* __restrict__ W3f, const float* __restrict__ b3,
    const float* __restrict__ W4, const float* __restrict__ b4,
    float* __restrict__ out) {
    __shared__ int4 Abuf[2][128 * 16];   // 2 x 32 KB
    __shared__ int idxAll[128 * 28];     // 14 KB; reused as Osum in tail

    int tid = threadIdx.x;
    int l = tid & 63, w = tid >> 6;
    int mw = w >> 1, nwv = w & 1;
    int wg = xcd_swz(blockIdx.x, gridDim.x);
    int v0 = wg * 128;

    for (int g = tid; g < KOFF * 128; g += 256) {
        int k = g >> 7, vi = g & 127;
        int v = v0 + vi;
        idxAll[vi * 28 + k] = (v < N_VOX) ? nidx[(size_t)k * N_VOX + v] : N_VOX;
    }
    __syncthreads();

    f32x4 acc[4][4];
#pragma unroll
    for (int m = 0; m < 4; ++m)
#pragma unroll
        for (int n = 0; n < 4; ++n) acc[m][n] = (f32x4)0.f;

    // prologue: stage k=0
    {
        int4 g0[8];
#pragma unroll
        for (int u = 0; u < 8; ++u) {
            int q = u * 256 + tid;
            int r = q >> 4, s = q & 15;
            int c = (s & 8) | ((s & 7) ^ (r & 7));
            int idx = idxAll[r * 28];
            g0[u] = *(const int4*)(h1b + (size_t)idx * CCH + c * 8);
        }
#pragma unroll
        for (int u = 0; u < 8; ++u) {
            int q = u * 256 + tid;
            Abuf[0][(q >> 4) * 16 + (q & 15)] = g0[u];
        }
    }
    __syncthreads();

    for (int k = 0; k < KOFF; ++k) {
        int cur = k & 1;
        size_t base = (size_t)k * 4 * 8 * 64 * 8;
        bf16x8 bA[4], bB[4];
        // b-frags for kk=0,1 BEFORE gather issue (vmcnt order: their waits
        // must not force the k+1 gathers to retire)
#pragma unroll
        for (int n = 0; n < 4; ++n) {
            int nf = nwv * 4 + n;
            bA[n] = *(const bf16x8*)(W2f + base + ((size_t)(0 * 8 + nf) * 64 + l) * 8);
            bB[n] = *(const bf16x8*)(W2f + base + ((size_t)(1 * 8 + nf) * 64 + l) * 8);
        }
        int4 gg[8];
        if (k + 1 < KOFF) {
#pragma unroll
            for (int u = 0; u < 8; ++u) {
                int q = u * 256 + tid;
                int r = q >> 4, s = q & 15;
                int c = (s & 8) | ((s & 7) ^ (r & 7));
                int idx = idxAll[r * 28 + k + 1];
                gg[u] = *(const int4*)(h1b + (size_t)idx * CCH + c * 8);
            }
        }
        // kk = 0,1 with preloaded frags
#pragma unroll
        for (int kk = 0; kk < 2; ++kk) {
            bf16x8 a[4];
#pragma unroll
            for (int m = 0; m < 4; ++m) {
                int r = mw * 64 + m * 16 + (l & 15);
                int c = kk * 4 + (l >> 4);
                int s = (c & 8) | ((c & 7) ^ (r & 7));
                a[m] = *(const bf16x8*)&Abuf[cur][r * 16 + s];
            }
            bf16x8* bb = kk ? bB : bA;
#pragma unroll
            for (int m = 0; m < 4; ++m)
#pragma unroll
                for (int n = 0; n < 4; ++n)
                    acc[m][n] = __builtin_amdgcn_mfma_f32_16x16x32_bf16(
                        a[m], bb[n], acc[m][n], 0, 0, 0);
        }
        // kk = 2,3: load frags now (issued after gathers; waits land >=2
        // MFMA-phases later, so gathers stay hidden)
#pragma unroll
        for (int n = 0; n < 4; ++n) {
            int nf = nwv * 4 + n;
            bA[n] = *(const bf16x8*)(W2f + base + ((size_t)(2 * 8 + nf) * 64 + l) * 8);
            bB[n] = *(const bf16x8*)(W2f + base + ((size_t)(3 * 8 + nf) * 64 + l) * 8);
        }
#pragma unroll
        for (int kk = 2; kk < 4; ++kk) {
            bf16x8 a[4];
#pragma unroll
            for (int m = 0; m < 4; ++m) {
                int r = mw * 64 + m * 16 + (l & 15);
                int c = kk * 4 + (l >> 4);
                int s = (c & 8) | ((c & 7) ^ (r & 7));
                a[m] = *(const bf16x8*)&Abuf[cur][r * 16 + s];
            }
            bf16x8* bb = (kk == 3) ? bB : bA;
#pragma unroll
            for (int m = 0; m < 4; ++m)
#pragma unroll
                for (int n = 0; n < 4; ++n)
                    acc[m][n] = __builtin_amdgcn_mfma_f32_16x16x32_bf16(
                        a[m], bb[n], acc[m][n], 0, 0, 0);
        }
        if (k + 1 < KOFF) {
#pragma unroll
            for (int u = 0; u < 8; ++u) {
                int q = u * 256 + tid;
                Abuf[cur ^ 1][(q >> 4) * 16 + (q & 15)] = gg[u];
            }
        }
        __syncthreads();
    }

    // ---- fused tail: H = bf16(silu(acc+b2)) -> LDS; P = H @ W3; out ----
    float bias2[4];
#pragma unroll
    for (int n = 0; n < 4; ++n) bias2[n] = b2[nwv * 64 + n * 16 + (l & 15)];
    unsigned short* H16 = (unsigned short*)&Abuf[0][0];
#pragma unroll
    for (int m = 0; m < 4; ++m) {
        int rbase = mw * 64 + m * 16 + (l >> 4) * 4;
#pragma unroll
        for (int n = 0; n < 4; ++n) {
            int ch = nwv * 64 + n * 16 + (l & 15);
            int c = ch >> 3;
            f32x4 d = acc[m][n];
#pragma unroll
            for (int ri = 0; ri < 4; ++ri) {
                int r = rbase + ri;
                int s = (c & 8) | ((c & 7) ^ (r & 7));
                H16[r * 128 + s * 8 + (ch & 7)] = f2bf(silu_f(d[ri] + bias2[n]));
            }
        }
    }
    __syncthreads();

    f32x4 p[4][4];
#pragma unroll
    for (int m = 0; m < 4; ++m)
#pragma unroll
        for (int n = 0; n < 4; ++n) p[m][n] = (f32x4)0.f;
#pragma unroll
    for (int kk = 0; kk < 4; ++kk) {
        bf16x8 a[4], b[4];
#pragma unroll
        for (int n = 0; n < 4; ++n) {
            int nf = nwv * 4 + n;
            b[n] = *(const bf16x8*)(W3f + ((size_t)(kk * 8 + nf) * 64 + l) * 8);
        }
#pragma unroll
        for (int m = 0; m < 4; ++m) {
            int r = mw * 64 + m * 16 + (l & 15);
            int c = kk * 4 + (l >> 4);
            int s = (c & 8) | ((c & 7) ^ (r & 7));
            a[m] = *(const bf16x8*)&Abuf[0][r * 16 + s];
        }
#pragma unroll
        for (int m = 0; m < 4; ++m)
#pragma unroll
            for (int n = 0; n < 4; ++n)
                p[m][n] = __builtin_amdgcn_mfma_f32_16x16x32_bf16(
                    a[m], b[n], p[m][n], 0, 0, 0);
    }

    float w4v[4], b3v[4];
#pragma unroll
    for (int n = 0; n < 4; ++n) {
        int ch = nwv * 64 + n * 16 + (l & 15);
        w4v[n] = W4[ch];
        b3v[n] = b3[ch];
    }
    float* Osum = (float*)idxAll;   // idxAll dead past this point
#pragma unroll
    for (int m = 0; m < 4; ++m) {
        float po[4] = {0.f, 0.f, 0.f, 0.f};
#pragma unroll
        for (int n = 0; n < 4; ++n) {
            f32x4 d = p[m][n];
#pragma unroll
            for (int ri = 0; ri < 4; ++ri)
                po[ri] += silu_f(d[ri] + b3v[n]) * w4v[n];
        }
#pragma unroll
        for (int off = 1; off < 16; off <<= 1)
#pragma unroll
            for (int ri = 0; ri < 4; ++ri)
                po[ri] += __shfl_xor(po[ri], off, 64);
        if ((l & 15) == 0) {
            int rbase = mw * 64 + m * 16 + (l >> 4) * 4;
#pragma unroll
            for (int ri = 0; ri < 4; ++ri)
                Osum[nwv * 128 + rbase + ri] = po[ri];
        }
    }
    __syncthreads();
    if (tid < 128) {
        int v = v0 + tid;
        if (v < N_VOX) out[v] = Osum[tid] + Osum[128 + tid] + b4[0];
    }
}

// ---------------------------------------------------------------------------
extern "C" void kernel_launch(void* const* d_in, const int* in_sizes, int n_in,
                              void* d_out, int out_size, void* d_ws,
                              size_t ws_size, hipStream_t stream) {
    const float* feat = (const float*)d_in[0];
    const int* t      = (const int*)d_in[1];
    const int* nidx   = (const int*)d_in[2];
    const float* W1   = (const float*)d_in[3];
    const float* b1   = (const float*)d_in[4];
    const float* W2   = (const float*)d_in[5];
    const float* b2   = (const float*)d_in[6];
    const float* W3   = (const float*)d_in[7];
    const float* b3   = (const float*)d_in[8];
    const float* W4   = (const float*)d_in[9];
    const float* b4   = (const float*)d_in[10];
    float* out = (float*)d_out;

    char* ws = (char*)d_ws;
    size_t off = 0;
    unsigned short* xeb = (unsigned short*)(ws + off);
    off += ((size_t)(N_VOX + 1) * 8 * 2 + 255) & ~(size_t)255;
    unsigned short* h1b = (unsigned short*)(ws + off);
    off += ((size_t)(N_VOX + 1) * CCH * 2 + 255) & ~(size_t)255;
    unsigned short* W1f = (unsigned short*)(ws + off);
    off += ((size_t)7 * 8 * 64 * 8 * 2 + 255) & ~(size_t)255;
    unsigned short* W2f = (unsigned short*)(ws + off);
    off += ((size_t)KOFF * 4 * 8 * 64 * 8 * 2 + 255) & ~(size_t)255;
    unsigned short* W3f = (unsigned short*)(ws + off);

    int grid = (N_VOX + 127) / 128;
    embed_kernel<<<(N_VOX + 1 + 255) / 256, 256, 0, stream>>>(feat, t, xeb);
    convert_w1<<<(7 * 8 * 64 + 255) / 256, 256, 0, stream>>>(W1, W1f);
    convert_w2<<<(KOFF * 4 * 8 * 64) / 256, 256, 0, stream>>>(W2, W2f);
    convert_w3<<<(4 * 8 * 64 + 255) / 256, 256, 0, stream>>>(W3, W3f);
    conv1_mfma<<<grid, 256, 0, stream>>>(xeb, nidx, W1f, b1, h1b);
    conv2_mfma<<<grid, 256, 0, stream>>>(h1b, nidx, W2f, b2, W3f, b3, W4, b4, out);
}

// Round 4
// 296.341 us; speedup vs baseline: 9.1631x; 1.1242x over previous
//
#include <hip/hip_runtime.h>
#include <math.h>

#define N_VOX 200000
#define CCH   128
#define KOFF  27

typedef __attribute__((ext_vector_type(8))) short bf16x8;
typedef __attribute__((ext_vector_type(4))) float f32x4;

__device__ __forceinline__ float silu_f(float x) {
    return x / (1.0f + expf(-x));
}
__device__ __forceinline__ unsigned short f2bf(float x) {
    unsigned int u = __float_as_uint(x);
    u = (u + 0x7FFFu + ((u >> 16) & 1u)) >> 16;
    return (unsigned short)u;
}
// bijective XCD-aware block swizzle (m204 variant)
__device__ __forceinline__ int xcd_swz(int orig, int nwg) {
    int q = nwg >> 3, r = nwg & 7;
    int xcd = orig & 7, pos = orig >> 3;
    return (xcd < r ? xcd * (q + 1) : r * (q + 1) + (xcd - r) * q) + pos;
}

// ---------------------------------------------------------------------------
// Kernel 1: time embedding -> bf16 xeb[(N+1)][8] = {feat, sin*3, cos*3, 0}
// ---------------------------------------------------------------------------
__global__ void embed_kernel(const float* __restrict__ feat,
                             const int* __restrict__ t,
                             unsigned short* __restrict__ xeb) {
    int i = blockIdx.x * blockDim.x + threadIdx.x;
    if (i > N_VOX) return;
    union { unsigned short u[8]; int4 v; } o;
    if (i == N_VOX) {
        o.v = make_int4(0, 0, 0, 0);
    } else {
        o.u[0] = f2bf(feat[i]);
        float tf = (float)t[i];
#pragma unroll
        for (int kk = 0; kk < 3; ++kk) {
            float freq = (float)M_PI * (float)(1 << kk);
            float ang = tf * freq;
            o.u[1 + kk] = f2bf(sinf(ang));
            o.u[4 + kk] = f2bf(cosf(ang));
        }
        o.u[7] = 0;
    }
    *(int4*)(xeb + (size_t)i * 8) = o.v;
}

// ---------------------------------------------------------------------------
// Weight repacks to MFMA-fragment-linear bf16 (B-operand layout).
// ---------------------------------------------------------------------------
__global__ void convert_w1(const float* __restrict__ W1,
                           unsigned short* __restrict__ W1f) {
    int g = blockIdx.x * 256 + threadIdx.x;
    if (g >= 7 * 8 * 64) return;
    int l = g & 63;
    int rest = g >> 6;
    int nf = rest & 7;
    int kk = rest >> 3;
    int o = kk * 4 + (l >> 4);
    int co = nf * 16 + (l & 15);
    union { unsigned short u[8]; int4 v; } out;
#pragma unroll
    for (int j = 0; j < 8; ++j) {
        float w = 0.f;
        if (o < KOFF && j < 7) w = W1[((size_t)o * 7 + j) * CCH + co];
        out.u[j] = f2bf(w);
    }
    *(int4*)(W1f + (size_t)g * 8) = out.v;
}

__global__ void convert_w2(const float* __restrict__ W2,
                           unsigned short* __restrict__ W2f) {
    int g = blockIdx.x * 256 + threadIdx.x;
    int l = g & 63;
    int rest = g >> 6;
    int nf = rest & 7;
    int kkk = rest >> 3;
    int k = kkk >> 2, kk = kkk & 3;
    int ci0 = kk * 32 + (l >> 4) * 8;
    int co = nf * 16 + (l & 15);
    union { unsigned short u[8]; int4 v; } out;
#pragma unroll
    for (int j = 0; j < 8; ++j)
        out.u[j] = f2bf(W2[((size_t)k * CCH + ci0 + j) * CCH + co]);
    *(int4*)(W2f + (size_t)g * 8) = out.v;
}

__global__ void convert_w3(const float* __restrict__ W3,
                           unsigned short* __restrict__ W3f) {
    int g = blockIdx.x * 256 + threadIdx.x;
    if (g >= 4 * 8 * 64) return;
    int l = g & 63;
    int rest = g >> 6;
    int nf = rest & 7;
    int kk = rest >> 3;
    int ci0 = kk * 32 + (l >> 4) * 8;
    int co = nf * 16 + (l & 15);
    union { unsigned short u[8]; int4 v; } out;
#pragma unroll
    for (int j = 0; j < 8; ++j)
        out.u[j] = f2bf(W3[(size_t)(ci0 + j) * CCH + co]);
    *(int4*)(W3f + (size_t)g * 8) = out.v;
}

// ---------------------------------------------------------------------------
// Kernel 2: conv1 via MFMA. 128 vox x 128 ch per block, K = 7 steps of 32.
// ---------------------------------------------------------------------------
__global__ __launch_bounds__(256) void conv1_mfma(
    const unsigned short* __restrict__ xeb, const int* __restrict__ nidx,
    const unsigned short* __restrict__ W1f, const float* __restrict__ b1,
    unsigned short* __restrict__ h1b) {
    __shared__ int4 bufmem[2048];
    __shared__ int idxAll[128 * 28];

    int tid = threadIdx.x;
    int l = tid & 63, w = tid >> 6;
    int mw = w >> 1, nwv = w & 1;
    int wg = xcd_swz(blockIdx.x, gridDim.x);
    int v0 = wg * 128;

    for (int g = tid; g < KOFF * 128; g += 256) {
        int k = g >> 7, vi = g & 127;
        int v = v0 + vi;
        idxAll[vi * 28 + k] = (v < N_VOX) ? nidx[(size_t)k * N_VOX + v] : N_VOX;
    }
    if (tid < 128) idxAll[tid * 28 + 27] = N_VOX;
    __syncthreads();

    f32x4 acc[4][4];
#pragma unroll
    for (int m = 0; m < 4; ++m)
#pragma unroll
        for (int n = 0; n < 4; ++n) acc[m][n] = (f32x4)0.f;

    {
        int4 g0[2]; int rr[2], cc[2];
#pragma unroll
        for (int u = 0; u < 2; ++u) {
            int q = u * 256 + tid;
            int r = q >> 2, oo = q & 3;
            int idx = idxAll[r * 28 + oo];
            g0[u] = *(const int4*)(xeb + (size_t)idx * 8);
            rr[u] = r; cc[u] = oo ^ (r & 3);
        }
#pragma unroll
        for (int u = 0; u < 2; ++u) bufmem[rr[u] * 5 + cc[u]] = g0[u];
    }
    __syncthreads();

    for (int kk = 0; kk < 7; ++kk) {
        int cur = kk & 1;
        int4 gg[2]; int rr[2], cc[2];
        if (kk < 6) {
#pragma unroll
            for (int u = 0; u < 2; ++u) {
                int q = u * 256 + tid;
                int r = q >> 2, oo = q & 3;
                int idx = idxAll[r * 28 + (kk + 1) * 4 + oo];
                gg[u] = *(const int4*)(xeb + (size_t)idx * 8);
                rr[u] = r; cc[u] = oo ^ (r & 3);
            }
        }
        bf16x8 a[4], b[4];
#pragma unroll
        for (int n = 0; n < 4; ++n) {
            int nf = nwv * 4 + n;
            b[n] = *(const bf16x8*)(W1f + ((size_t)(kk * 8 + nf) * 64 + l) * 8);
        }
#pragma unroll
        for (int m = 0; m < 4; ++m) {
            int r = mw * 64 + m * 16 + (l & 15);
            int c = l >> 4;
            a[m] = *(const bf16x8*)&bufmem[cur * 640 + r * 5 + (c ^ (r & 3))];
        }
#pragma unroll
        for (int m = 0; m < 4; ++m)
#pragma unroll
            for (int n = 0; n < 4; ++n)
                acc[m][n] = __builtin_amdgcn_mfma_f32_16x16x32_bf16(
                    a[m], b[n], acc[m][n], 0, 0, 0);
        if (kk < 6) {
#pragma unroll
            for (int u = 0; u < 2; ++u)
                bufmem[(cur ^ 1) * 640 + rr[u] * 5 + cc[u]] = gg[u];
        }
        __syncthreads();
    }

    float bias[4];
#pragma unroll
    for (int n = 0; n < 4; ++n) bias[n] = b1[nwv * 64 + n * 16 + (l & 15)];
    unsigned short* H16 = (unsigned short*)bufmem;
#pragma unroll
    for (int m = 0; m < 4; ++m) {
        int rbase = mw * 64 + m * 16 + (l >> 4) * 4;
#pragma unroll
        for (int n = 0; n < 4; ++n) {
            int ch = nwv * 64 + n * 16 + (l & 15);
            int c = ch >> 3;
            f32x4 d = acc[m][n];
#pragma unroll
            for (int ri = 0; ri < 4; ++ri) {
                int r = rbase + ri;
                int s = (c & 8) | ((c & 7) ^ (r & 7));
                H16[r * 128 + s * 8 + (ch & 7)] = f2bf(silu_f(d[ri] + bias[n]));
            }
        }
    }
    __syncthreads();
#pragma unroll
    for (int u = 0; u < 8; ++u) {
        int q = u * 256 + tid;
        int r = q >> 4, s = q & 15;
        int c = (s & 8) | ((s & 7) ^ (r & 7));
        int v = v0 + r;
        if (v < N_VOX)
            *(int4*)(h1b + (size_t)v * CCH + c * 8) = bufmem[r * 16 + s];
    }
    if (blockIdx.x == 0 && tid < 16)
        *(int4*)(h1b + (size_t)N_VOX * CCH + tid * 8) = make_int4(0, 0, 0, 0);
}

// ---------------------------------------------------------------------------
// Kernel 3: conv2 via MFMA + fused tail. BM=64 voxels x 128 ch per block:
// LDS = 32KB dbuf A-tile + 7KB idx -> 4 blocks/CU (16 waves) for latency
// hiding. __launch_bounds__(256,4) caps VGPR at 128.
// ---------------------------------------------------------------------------
__global__ __launch_bounds__(256, 4) void conv2_mfma(
    const unsigned short* __restrict__ h1b, const int* __restrict__ nidx,
    const unsigned short* __restrict__ W2f, const float* __restrict__ b2,
    const unsigned short* __restrict__ W3f, const float* __restrict__ b3,
    const float* __restrict__ W4, const float* __restrict__ b4,
    float* __restrict__ out) {
    __shared__ int4 Abuf[2][64 * 16];    // 2 x 16 KB
    __shared__ int idxAll[28 * 64];      // [k][vi], 7 KB; reused as Osum

    int tid = threadIdx.x;
    int l = tid & 63, w = tid >> 6;
    int mw = w >> 1, nwv = w & 1;
    int wg = xcd_swz(blockIdx.x, gridDim.x);
    int v0 = wg * 64;

    for (int g = tid; g < KOFF * 64; g += 256) {
        int k = g >> 6, vi = g & 63;
        int v = v0 + vi;
        idxAll[k * 64 + vi] = (v < N_VOX) ? nidx[(size_t)k * N_VOX + v] : N_VOX;
    }
    __syncthreads();

    f32x4 acc[2][4];
#pragma unroll
    for (int m = 0; m < 2; ++m)
#pragma unroll
        for (int n = 0; n < 4; ++n) acc[m][n] = (f32x4)0.f;

    // prologue: stage k=0 (4 slot-loads per thread; 16 lanes per row)
    {
        int4 g0[4];
#pragma unroll
        for (int u = 0; u < 4; ++u) {
            int q = u * 256 + tid;
            int r = q >> 4, s = q & 15;
            int c = (s & 8) | ((s & 7) ^ (r & 7));
            int idx = idxAll[r];
            g0[u] = *(const int4*)(h1b + (size_t)idx * CCH + c * 8);
        }
#pragma unroll
        for (int u = 0; u < 4; ++u) {
            int q = u * 256 + tid;
            Abuf[0][(q >> 4) * 16 + (q & 15)] = g0[u];
        }
    }
    __syncthreads();

    for (int k = 0; k < KOFF; ++k) {
        int cur = k & 1;
        size_t base = (size_t)k * 4 * 8 * 64 * 8;
        bf16x8 bA[4], bB[4];
#pragma unroll
        for (int n = 0; n < 4; ++n) {
            int nf = nwv * 4 + n;
            bA[n] = *(const bf16x8*)(W2f + base + ((size_t)(0 * 8 + nf) * 64 + l) * 8);
            bB[n] = *(const bf16x8*)(W2f + base + ((size_t)(1 * 8 + nf) * 64 + l) * 8);
        }
        int4 gg[4];
        if (k + 1 < KOFF) {
#pragma unroll
            for (int u = 0; u < 4; ++u) {
                int q = u * 256 + tid;
                int r = q >> 4, s = q & 15;
                int c = (s & 8) | ((s & 7) ^ (r & 7));
                int idx = idxAll[(k + 1) * 64 + r];
                gg[u] = *(const int4*)(h1b + (size_t)idx * CCH + c * 8);
            }
        }
#pragma unroll
        for (int kk = 0; kk < 2; ++kk) {
            bf16x8 a[2];
#pragma unroll
            for (int m = 0; m < 2; ++m) {
                int r = mw * 32 + m * 16 + (l & 15);
                int c = kk * 4 + (l >> 4);
                int s = (c & 8) | ((c & 7) ^ (r & 7));
                a[m] = *(const bf16x8*)&Abuf[cur][r * 16 + s];
            }
            bf16x8* bb = kk ? bB : bA;
#pragma unroll
            for (int m = 0; m < 2; ++m)
#pragma unroll
                for (int n = 0; n < 4; ++n)
                    acc[m][n] = __builtin_amdgcn_mfma_f32_16x16x32_bf16(
                        a[m], bb[n], acc[m][n], 0, 0, 0);
        }
#pragma unroll
        for (int n = 0; n < 4; ++n) {
            int nf = nwv * 4 + n;
            bA[n] = *(const bf16x8*)(W2f + base + ((size_t)(2 * 8 + nf) * 64 + l) * 8);
            bB[n] = *(const bf16x8*)(W2f + base + ((size_t)(3 * 8 + nf) * 64 + l) * 8);
        }
#pragma unroll
        for (int kk = 2; kk < 4; ++kk) {
            bf16x8 a[2];
#pragma unroll
            for (int m = 0; m < 2; ++m) {
                int r = mw * 32 + m * 16 + (l & 15);
                int c = kk * 4 + (l >> 4);
                int s = (c & 8) | ((c & 7) ^ (r & 7));
                a[m] = *(const bf16x8*)&Abuf[cur][r * 16 + s];
            }
            bf16x8* bb = (kk == 3) ? bB : bA;
#pragma unroll
            for (int m = 0; m < 2; ++m)
#pragma unroll
                for (int n = 0; n < 4; ++n)
                    acc[m][n] = __builtin_amdgcn_mfma_f32_16x16x32_bf16(
                        a[m], bb[n], acc[m][n], 0, 0, 0);
        }
        if (k + 1 < KOFF) {
#pragma unroll
            for (int u = 0; u < 4; ++u) {
                int q = u * 256 + tid;
                Abuf[cur ^ 1][(q >> 4) * 16 + (q & 15)] = gg[u];
            }
        }
        __syncthreads();
    }

    // ---- fused tail: H = bf16(silu(acc+b2)) -> LDS; P = H @ W3; out ----
    float bias2[4];
#pragma unroll
    for (int n = 0; n < 4; ++n) bias2[n] = b2[nwv * 64 + n * 16 + (l & 15)];
    unsigned short* H16 = (unsigned short*)&Abuf[0][0];
#pragma unroll
    for (int m = 0; m < 2; ++m) {
        int rbase = mw * 32 + m * 16 + (l >> 4) * 4;
#pragma unroll
        for (int n = 0; n < 4; ++n) {
            int ch = nwv * 64 + n * 16 + (l & 15);
            int c = ch >> 3;
            f32x4 d = acc[m][n];
#pragma unroll
            for (int ri = 0; ri < 4; ++ri) {
                int r = rbase + ri;
                int s = (c & 8) | ((c & 7) ^ (r & 7));
                H16[r * 128 + s * 8 + (ch & 7)] = f2bf(silu_f(d[ri] + bias2[n]));
            }
        }
    }
    __syncthreads();

    f32x4 p[2][4];
#pragma unroll
    for (int m = 0; m < 2; ++m)
#pragma unroll
        for (int n = 0; n < 4; ++n) p[m][n] = (f32x4)0.f;
#pragma unroll
    for (int kk = 0; kk < 4; ++kk) {
        bf16x8 a[2], b[4];
#pragma unroll
        for (int n = 0; n < 4; ++n) {
            int nf = nwv * 4 + n;
            b[n] = *(const bf16x8*)(W3f + ((size_t)(kk * 8 + nf) * 64 + l) * 8);
        }
#pragma unroll
        for (int m = 0; m < 2; ++m) {
            int r = mw * 32 + m * 16 + (l & 15);
            int c = kk * 4 + (l >> 4);
            int s = (c & 8) | ((c & 7) ^ (r & 7));
            a[m] = *(const bf16x8*)&Abuf[0][r * 16 + s];
        }
#pragma unroll
        for (int m = 0; m < 2; ++m)
#pragma unroll
            for (int n = 0; n < 4; ++n)
                p[m][n] = __builtin_amdgcn_mfma_f32_16x16x32_bf16(
                    a[m], b[n], p[m][n], 0, 0, 0);
    }

    float w4v[4], b3v[4];
#pragma unroll
    for (int n = 0; n < 4; ++n) {
        int ch = nwv * 64 + n * 16 + (l & 15);
        w4v[n] = W4[ch];
        b3v[n] = b3[ch];
    }
    float* Osum = (float*)idxAll;
#pragma unroll
    for (int m = 0; m < 2; ++m) {
        float po[4] = {0.f, 0.f, 0.f, 0.f};
#pragma unroll
        for (int n = 0; n < 4; ++n) {
            f32x4 d = p[m][n];
#pragma unroll
            for (int ri = 0; ri < 4; ++ri)
                po[ri] += silu_f(d[ri] + b3v[n]) * w4v[n];
        }
#pragma unroll
        for (int off = 1; off < 16; off <<= 1)
#pragma unroll
            for (int ri = 0; ri < 4; ++ri)
                po[ri] += __shfl_xor(po[ri], off, 64);
        if ((l & 15) == 0) {
            int rbase = mw * 32 + m * 16 + (l >> 4) * 4;
#pragma unroll
            for (int ri = 0; ri < 4; ++ri)
                Osum[nwv * 64 + rbase + ri] = po[ri];
        }
    }
    __syncthreads();
    if (tid < 64) {
        int v = v0 + tid;
        if (v < N_VOX) out[v] = Osum[tid] + Osum[64 + tid] + b4[0];
    }
}

// ---------------------------------------------------------------------------
extern "C" void kernel_launch(void* const* d_in, const int* in_sizes, int n_in,
                              void* d_out, int out_size, void* d_ws,
                              size_t ws_size, hipStream_t stream) {
    const float* feat = (const float*)d_in[0];
    const int* t      = (const int*)d_in[1];
    const int* nidx   = (const int*)d_in[2];
    const float* W1   = (const float*)d_in[3];
    const float* b1   = (const float*)d_in[4];
    const float* W2   = (const float*)d_in[5];
    const float* b2   = (const float*)d_in[6];
    const float* W3   = (const float*)d_in[7];
    const float* b3   = (const float*)d_in[8];
    const float* W4   = (const float*)d_in[9];
    const float* b4   = (const float*)d_in[10];
    float* out = (float*)d_out;

    char* ws = (char*)d_ws;
    size_t off = 0;
    unsigned short* xeb = (unsigned short*)(ws + off);
    off += ((size_t)(N_VOX + 1) * 8 * 2 + 255) & ~(size_t)255;
    unsigned short* h1b = (unsigned short*)(ws + off);
    off += ((size_t)(N_VOX + 1) * CCH * 2 + 255) & ~(size_t)255;
    unsigned short* W1f = (unsigned short*)(ws + off);
    off += ((size_t)7 * 8 * 64 * 8 * 2 + 255) & ~(size_t)255;
    unsigned short* W2f = (unsigned short*)(ws + off);
    off += ((size_t)KOFF * 4 * 8 * 64 * 8 * 2 + 255) & ~(size_t)255;
    unsigned short* W3f = (unsigned short*)(ws + off);

    int grid1 = (N_VOX + 127) / 128;
    int grid2 = (N_VOX + 63) / 64;
    embed_kernel<<<(N_VOX + 1 + 255) / 256, 256, 0, stream>>>(feat, t, xeb);
    convert_w1<<<(7 * 8 * 64 + 255) / 256, 256, 0, stream>>>(W1, W1f);
    convert_w2<<<(KOFF * 4 * 8 * 64) / 256, 256, 0, stream>>>(W2, W2f);
    convert_w3<<<(4 * 8 * 64 + 255) / 256, 256, 0, stream>>>(W3, W3f);
    conv1_mfma<<<grid1, 256, 0, stream>>>(xeb, nidx, W1f, b1, h1b);
    conv2_mfma<<<grid2, 256, 0, stream>>>(h1b, nidx, W2f, b2, W3f, b3, W4, b4, out);
}